// Round 8
// baseline (1701.308 us; speedup 1.0000x reference)
//
#include <hip/hip_runtime.h>

#define N_NODES 10000
#define N_EDGES 160000
#define IN_CH 128
#define H 64
#define H2 128
#define OUT_CH 112
#define NLAYERS 28
#define LOG2E 1.44269504088896340736f

// async global->LDS, 16B per lane, LDS dest = wave-uniform base + lane*16
#define GLDS16(gp, lp) __builtin_amdgcn_global_load_lds( \
    (const __attribute__((address_space(1))) void*)(gp),  \
    (__attribute__((address_space(3))) void*)(lp), 16, 0, 0)

// ---------------- CSR build ----------------
__global__ __launch_bounds__(256) void k_count(const int* __restrict__ ei, int* __restrict__ deg) {
  int e = blockIdx.x * 256 + threadIdx.x;
  atomicAdd(&deg[ei[N_EDGES + e]], 1);   // E = 625*256 exactly
}

__global__ __launch_bounds__(1024) void k_scan(const int* __restrict__ deg, int* __restrict__ offs) {
  __shared__ int sums[1024];
  constexpr int CH = 10;
  int t = threadIdx.x;
  int base = t * CH;
  int local[CH];
  int s = 0;
  #pragma unroll
  for (int i = 0; i < CH; i++) {
    int idx = base + i;
    int v = (idx < N_NODES) ? deg[idx] : 0;
    local[i] = s; s += v;
  }
  sums[t] = s;
  __syncthreads();
  for (int off = 1; off < 1024; off <<= 1) {
    int v = (t >= off) ? sums[t - off] : 0;
    __syncthreads();
    sums[t] += v;
    __syncthreads();
  }
  int prev = (t == 0) ? 0 : sums[t - 1];
  #pragma unroll
  for (int i = 0; i < CH; i++) {
    int idx = base + i;
    if (idx < N_NODES) offs[idx] = prev + local[i];
  }
  if (t == 1023) offs[N_NODES] = sums[1023];
}

// csr stores BYTE offsets (src*H*4) to shave gather addressing
__global__ __launch_bounds__(256) void k_fill(const int* __restrict__ ei, const int* __restrict__ offs,
                                              int* __restrict__ cur, int* __restrict__ csr) {
  int e = blockIdx.x * 256 + threadIdx.x;
  int d = ei[N_EDGES + e];
  int p = offs[d] + atomicAdd(&cur[d], 1);
  csr[p] = ei[e] << 8;
}

// ---------------- weight packing ----------------
// W1P[l][g*512 + h*256 + lane*4 + e] = W1[l][(4g + h*2 + (e>>1))*128 + lane*2 + (e&1)]
//   -> LDS reads are contiguous 16B/lane slots (conflict-free ds_read_b128).
// W2P[l][(g*64+lane)*4 + j] = W2[l][(4g+j)*64 + lane]   (streamed from global)
__global__ __launch_bounds__(256) void k_pack(const float* __restrict__ W1, const float* __restrict__ W2,
                                              float* __restrict__ W1P, float* __restrict__ W2P) {
  int l = blockIdx.x;
  const float* w1 = W1 + l * 8192; float* p1 = W1P + l * 8192;
  const float* w2 = W2 + l * 8192; float* p2 = W2P + l * 8192;
  int t = threadIdx.x;
  for (int i = t; i < 8192; i += 256) {
    int g = i >> 9, r = i & 511;
    int hh = r >> 8, lane = (r >> 2) & 63, e = r & 3;
    p1[i] = w1[(4 * g + hh * 2 + (e >> 1)) * H2 + lane * 2 + (e & 1)];
  }
  for (int i = t; i < 8192; i += 256) {
    int g = i >> 8, r = i & 255;
    int lane = r >> 2, j = r & 3;
    p2[i] = w2[(4 * g + j) * H + lane];
  }
}

// ---------------- encoder: h = x@W+b ; z0 = relu(LN(h; g0,b0)) ----------------
__global__ __launch_bounds__(256) void k_encoder(
    const float* __restrict__ x, const float* __restrict__ Wenc, const float* __restrict__ benc,
    const float* __restrict__ lng, const float* __restrict__ lnb,
    float* __restrict__ h, float* __restrict__ z) {
  __shared__ float Xs[8][IN_CH];
  int t = threadIdx.x;
  int tile = blockIdx.x * 8;
  {
    int r = t >> 5, c4 = t & 31;
    float4 v = ((const float4*)x)[(tile + r) * 32 + c4];
    *(float4*)&Xs[r][c4 * 4] = v;
  }
  __syncthreads();
  int lane = t & 63;
  int wave = __builtin_amdgcn_readfirstlane(t >> 6);
  int n0 = wave * 2;
  float b = benc[lane];
  float a0 = b, a1 = b;
  #pragma unroll
  for (int k = 0; k < IN_CH; k += 4) {
    float4 X0 = *(float4*)&Xs[n0][k];
    float4 X1 = *(float4*)&Xs[n0 + 1][k];
    float w0 = Wenc[(k + 0) * H + lane];
    float w1 = Wenc[(k + 1) * H + lane];
    float w2 = Wenc[(k + 2) * H + lane];
    float w3 = Wenc[(k + 3) * H + lane];
    a0 = fmaf(X0.x, w0, a0); a0 = fmaf(X0.y, w1, a0); a0 = fmaf(X0.z, w2, a0); a0 = fmaf(X0.w, w3, a0);
    a1 = fmaf(X1.x, w0, a1); a1 = fmaf(X1.y, w1, a1); a1 = fmaf(X1.z, w2, a1); a1 = fmaf(X1.w, w3, a1);
  }
  float g = lng[lane], bb = lnb[lane];
  #pragma unroll
  for (int i = 0; i < 2; i++) {
    float a = (i == 0) ? a0 : a1;
    float s = a, q = a * a;
    #pragma unroll
    for (int m = 1; m < 64; m <<= 1) { s += __shfl_xor(s, m); q += __shfl_xor(q, m); }
    float mu = s * (1.0f / 64.0f);
    float var = q * (1.0f / 64.0f) - mu * mu;
    float rs = rsqrtf(var + 1e-5f);
    int gn = tile + n0 + i;
    h[gn * H + lane] = a;
    z[gn * H + lane] = fmaxf(fmaf((a - mu) * rs, g, bb), 0.f);
  }
}

// ---------------- fused GENConv layer ----------------
// 1000 blocks x 4 waves; waves 0,1 -> 3 nodes, waves 2,3 -> 2 nodes (10/block).
// W1 (32KB) async-staged to LDS under agg; W2 streamed from global (L1-hot).
__global__ __launch_bounds__(256, 4) void k_layer(
    const float* __restrict__ zc, float* __restrict__ zn, float* __restrict__ h,
    const int* __restrict__ offs, const int* __restrict__ csr,
    const float* __restrict__ tvec,
    const float* __restrict__ W1P, const float* __restrict__ W2P,
    const float* __restrict__ b1,
    const float* __restrict__ mg, const float* __restrict__ mb,
    const float* __restrict__ b2,
    const float* __restrict__ lngn, const float* __restrict__ lnbn,
    int l, int last) {
  __shared__ float Ws[8192];       // 32 KB W1
  __shared__ float Asl[10][H];     // 2.5 KB
  __shared__ float Us[10][H2];     // 5 KB
  int t = threadIdx.x;
  int lane = t & 63;
  int wave = __builtin_amdgcn_readfirstlane(t >> 6);
  int tile = blockIdx.x * 10;

  // async W1 stage (oldest in vmcnt queue; completes under agg)
  const float* W1Pl = W1P + (size_t)l * 8192;
  #pragma unroll
  for (int i = 0; i < 8; i++) {
    int off = (i * 256 + t) * 4;
    GLDS16(W1Pl + off, Ws + off);
  }

  int s = (wave < 2) ? wave * 3 : 6 + (wave - 2) * 2;
  int cnt = (wave < 2) ? 3 : 2;

  // ---- phase A: softmax aggregation, 16-wide interleaved first round ----
  float tl = tvec[l] * LOG2E;
  int e0[3], e1[3], nd[3];
  #pragma unroll
  for (int i = 0; i < 3; i++) {
    nd[i] = tile + s + ((i < cnt) ? i : cnt - 1);   // clamped (dup) node for spare slot
    e0[i] = offs[nd[i]]; e1[i] = offs[nd[i] + 1];
  }
  float den[3] = {0.f, 0.f, 0.f}, acc[3] = {0.f, 0.f, 0.f};
  {
    int idx[3][16];
    #pragma unroll
    for (int i = 0; i < 3; i++) {
      if (i < cnt) {
        #pragma unroll
        for (int j = 0; j < 16; j++) {
          int ee = e0[i] + j;
          int ce = ee < e1[i] ? ee : e1[i] - 1;
          idx[i][j] = csr[ce < 0 ? 0 : ce];
        }
      }
    }
    float vv[3][16];
    #pragma unroll
    for (int i = 0; i < 3; i++) {
      if (i < cnt) {
        #pragma unroll
        for (int j = 0; j < 16; j++)
          vv[i][j] = *(const float*)((const char*)zc + idx[i][j] + (lane << 2));
      }
    }
    #pragma unroll
    for (int i = 0; i < 3; i++) {
      if (i < cnt) {
        #pragma unroll
        for (int j = 0; j < 16; j++) {
          float v = vv[i][j] + 1e-7f;
          float pz = (e0[i] + j < e1[i]) ? __builtin_amdgcn_exp2f(v * tl) : 0.f;
          den[i] += pz;
          acc[i] = fmaf(pz, v, acc[i]);
        }
      }
    }
  }
  // tail rounds (deg > 16)
  #pragma unroll
  for (int i = 0; i < 3; i++) {
    if (i < cnt) {
      for (int base = e0[i] + 16; base < e1[i]; base += 16) {
        int id2[16]; float v2[16];
        #pragma unroll
        for (int j = 0; j < 16; j++) {
          int ee = base + j;
          id2[j] = csr[ee < e1[i] ? ee : e1[i] - 1];
        }
        #pragma unroll
        for (int j = 0; j < 16; j++)
          v2[j] = *(const float*)((const char*)zc + id2[j] + (lane << 2));
        #pragma unroll
        for (int j = 0; j < 16; j++) {
          float v = v2[j] + 1e-7f;
          float pz = (base + j < e1[i]) ? __builtin_amdgcn_exp2f(v * tl) : 0.f;
          den[i] += pz;
          acc[i] = fmaf(pz, v, acc[i]);
        }
      }
    }
  }
  #pragma unroll
  for (int i = 0; i < 3; i++) {
    if (i < cnt) {   // FIX(R7): dup slot must NOT write — its acc/den were never computed
      Asl[s + i][lane] = acc[i] / (den[i] + 1e-16f) + zc[nd[i] * H + lane];
    }
  }

  __syncthreads();   // drains vmcnt(0): W1 in LDS; Asl visible

  // ---- phase B: u1 = A @ W1 + b1 ; Us = relu(LN(u1)) ----
  {
    const float* b1l = b1 + l * H2;
    int c0 = lane * 2;
    float bb0 = b1l[c0], bb1 = b1l[c0 + 1];
    float u0[3], u1[3];
    #pragma unroll
    for (int i = 0; i < 3; i++) { u0[i] = bb0; u1[i] = bb1; }
    int r0 = s, r1 = s + 1, r2 = s + cnt - 1;
    #pragma unroll
    for (int g = 0; g < 16; g++) {
      float4 wa = *(float4*)&Ws[g * 512 + lane * 4];
      float4 wb = *(float4*)&Ws[g * 512 + 256 + lane * 4];
      float4 A0 = *(float4*)&Asl[r0][g * 4];
      float4 A1 = *(float4*)&Asl[r1][g * 4];
      float4 A2 = *(float4*)&Asl[r2][g * 4];
      u0[0] = fmaf(A0.x, wa.x, u0[0]); u1[0] = fmaf(A0.x, wa.y, u1[0]);
      u0[0] = fmaf(A0.y, wa.z, u0[0]); u1[0] = fmaf(A0.y, wa.w, u1[0]);
      u0[0] = fmaf(A0.z, wb.x, u0[0]); u1[0] = fmaf(A0.z, wb.y, u1[0]);
      u0[0] = fmaf(A0.w, wb.z, u0[0]); u1[0] = fmaf(A0.w, wb.w, u1[0]);
      u0[1] = fmaf(A1.x, wa.x, u0[1]); u1[1] = fmaf(A1.x, wa.y, u1[1]);
      u0[1] = fmaf(A1.y, wa.z, u0[1]); u1[1] = fmaf(A1.y, wa.w, u1[1]);
      u0[1] = fmaf(A1.z, wb.x, u0[1]); u1[1] = fmaf(A1.z, wb.y, u1[1]);
      u0[1] = fmaf(A1.w, wb.z, u0[1]); u1[1] = fmaf(A1.w, wb.w, u1[1]);
      u0[2] = fmaf(A2.x, wa.x, u0[2]); u1[2] = fmaf(A2.x, wa.y, u1[2]);
      u0[2] = fmaf(A2.y, wa.z, u0[2]); u1[2] = fmaf(A2.y, wa.w, u1[2]);
      u0[2] = fmaf(A2.z, wb.x, u0[2]); u1[2] = fmaf(A2.z, wb.y, u1[2]);
      u0[2] = fmaf(A2.w, wb.z, u0[2]); u1[2] = fmaf(A2.w, wb.w, u1[2]);
    }
    float sv[3], q[3];
    #pragma unroll
    for (int i = 0; i < 3; i++) { sv[i] = u0[i] + u1[i]; q[i] = u0[i] * u0[i] + u1[i] * u1[i]; }
    #pragma unroll
    for (int m = 1; m < 64; m <<= 1) {
      #pragma unroll
      for (int i = 0; i < 3; i++) { sv[i] += __shfl_xor(sv[i], m); q[i] += __shfl_xor(q[i], m); }
    }
    const float* mgl = mg + l * H2;
    const float* mbl = mb + l * H2;
    float g0 = mgl[c0], g1 = mgl[c0 + 1], hb0 = mbl[c0], hb1 = mbl[c0 + 1];
    #pragma unroll
    for (int i = 0; i < 3; i++) {
      if (i < cnt) {   // FIX(R7): guard dup slot
        float mu = sv[i] * (1.0f / 128.0f);
        float rs = rsqrtf(q[i] * (1.0f / 128.0f) - mu * mu + 1e-5f);
        float o0 = fmaxf(fmaf((u0[i] - mu) * rs, g0, hb0), 0.f);
        float o1 = fmaxf(fmaf((u1[i] - mu) * rs, g1, hb1), 0.f);
        *(float2*)&Us[s + i][c0] = make_float2(o0, o1);
      }
    }
  }
  // no barrier: phase C reads only own-wave Us rows (same-wave LDS RAW -> lgkmcnt)

  // ---- phase C: u2 = Us @ W2 + b2 ; h += u2 ; phase D: z_next = relu(LN(h)) ----
  {
    const float* W2Pl = W2P + (size_t)l * 8192;
    const float* b2l = b2 + l * H;
    float bb = b2l[lane];
    float v[3];
    #pragma unroll
    for (int i = 0; i < 3; i++) v[i] = bb;
    int r0 = s, r1 = s + 1, r2 = s + cnt - 1;
    #pragma unroll
    for (int g = 0; g < 32; g++) {
      float4 w = *(const float4*)&W2Pl[(g * 64 + lane) * 4];
      float4 X0 = *(float4*)&Us[r0][g * 4];
      float4 X1 = *(float4*)&Us[r1][g * 4];
      float4 X2 = *(float4*)&Us[r2][g * 4];
      v[0] = fmaf(X0.x, w.x, v[0]); v[0] = fmaf(X0.y, w.y, v[0]);
      v[0] = fmaf(X0.z, w.z, v[0]); v[0] = fmaf(X0.w, w.w, v[0]);
      v[1] = fmaf(X1.x, w.x, v[1]); v[1] = fmaf(X1.y, w.y, v[1]);
      v[1] = fmaf(X1.z, w.z, v[1]); v[1] = fmaf(X1.w, w.w, v[1]);
      v[2] = fmaf(X2.x, w.x, v[2]); v[2] = fmaf(X2.y, w.y, v[2]);
      v[2] = fmaf(X2.z, w.z, v[2]); v[2] = fmaf(X2.w, w.w, v[2]);
    }
    float gg = lngn[lane], gb = lnbn[lane];
    #pragma unroll
    for (int i = 0; i < 3; i++) {
      if (i < cnt) {
        int gn = nd[i];
        float hv = h[gn * H + lane] + v[i];
        h[gn * H + lane] = hv;
        if (!last) {
          float sv = hv, q = hv * hv;
          #pragma unroll
          for (int m = 1; m < 64; m <<= 1) { sv += __shfl_xor(sv, m); q += __shfl_xor(q, m); }
          float mu = sv * (1.0f / 64.0f);
          float rs = rsqrtf(q * (1.0f / 64.0f) - mu * mu + 1e-5f);
          zn[gn * H + lane] = fmaxf(fmaf((hv - mu) * rs, gg, gb), 0.f);
        }
      }
    }
  }
}

// ---------------- head: out = h @ Wh + bh ----------------
__global__ __launch_bounds__(256) void k_head(const float* __restrict__ h, const float* __restrict__ Wh,
                                              const float* __restrict__ bh, float* __restrict__ out) {
  __shared__ float Hs[8][H];
  int t = threadIdx.x;
  int tile = blockIdx.x * 8;
  if (t < 128) {
    int r = t >> 4, c4 = t & 15;
    float4 v = ((const float4*)h)[(tile + r) * 16 + c4];
    *(float4*)&Hs[r][c4 * 4] = v;
  }
  __syncthreads();
  int lane = t & 63;
  int wave = __builtin_amdgcn_readfirstlane(t >> 6);
  int n0 = wave * 2;
  int c2 = 64 + ((lane < 48) ? lane : 47);
  float b0 = bh[lane], b1 = bh[c2];
  float a00 = b0, a01 = b1, a10 = b0, a11 = b1;
  #pragma unroll
  for (int k = 0; k < H; k += 4) {
    float4 X0 = *(float4*)&Hs[n0][k];
    float4 X1 = *(float4*)&Hs[n0 + 1][k];
    float wA0 = Wh[(k + 0) * OUT_CH + lane], wB0 = Wh[(k + 0) * OUT_CH + c2];
    float wA1 = Wh[(k + 1) * OUT_CH + lane], wB1 = Wh[(k + 1) * OUT_CH + c2];
    float wA2 = Wh[(k + 2) * OUT_CH + lane], wB2 = Wh[(k + 2) * OUT_CH + c2];
    float wA3 = Wh[(k + 3) * OUT_CH + lane], wB3 = Wh[(k + 3) * OUT_CH + c2];
    a00 = fmaf(X0.x, wA0, a00); a01 = fmaf(X0.x, wB0, a01);
    a00 = fmaf(X0.y, wA1, a00); a01 = fmaf(X0.y, wB1, a01);
    a00 = fmaf(X0.z, wA2, a00); a01 = fmaf(X0.z, wB2, a01);
    a00 = fmaf(X0.w, wA3, a00); a01 = fmaf(X0.w, wB3, a01);
    a10 = fmaf(X1.x, wA0, a10); a11 = fmaf(X1.x, wB0, a11);
    a10 = fmaf(X1.y, wA1, a10); a11 = fmaf(X1.y, wB1, a11);
    a10 = fmaf(X1.z, wA2, a10); a11 = fmaf(X1.z, wB2, a11);
    a10 = fmaf(X1.w, wA3, a10); a11 = fmaf(X1.w, wB3, a11);
  }
  int gn0 = tile + n0;
  out[gn0 * OUT_CH + lane] = a00;
  out[(gn0 + 1) * OUT_CH + lane] = a10;
  if (lane < 48) {
    out[gn0 * OUT_CH + 64 + lane] = a01;
    out[(gn0 + 1) * OUT_CH + 64 + lane] = a11;
  }
}

extern "C" void kernel_launch(void* const* d_in, const int* in_sizes, int n_in,
                              void* d_out, int out_size, void* d_ws, size_t ws_size,
                              hipStream_t stream) {
  (void)in_sizes; (void)n_in; (void)out_size; (void)ws_size;
  const float* x    = (const float*)d_in[0];
  const int*   ei   = (const int*)d_in[1];
  const float* encW = (const float*)d_in[2];
  const float* encb = (const float*)d_in[3];
  const float* lng  = (const float*)d_in[4];
  const float* lnb  = (const float*)d_in[5];
  const float* tv   = (const float*)d_in[6];
  const float* W1   = (const float*)d_in[7];
  const float* b1   = (const float*)d_in[8];
  const float* mg   = (const float*)d_in[9];
  const float* mb   = (const float*)d_in[10];
  const float* W2   = (const float*)d_in[11];
  const float* b2   = (const float*)d_in[12];
  const float* Wh   = (const float*)d_in[13];
  const float* bh   = (const float*)d_in[14];

  char* ws = (char*)d_ws;
  int*   deg  = (int*)(ws + 0);            // N ints
  int*   cur  = (int*)(ws + 40000);        // N ints
  int*   offs = (int*)(ws + 80000);        // N+1 ints
  int*   csr  = (int*)(ws + 120064);       // E ints (byte offsets)
  float* h    = (float*)(ws + 760064);     // N*64
  float* z0   = (float*)(ws + 3320064);    // N*64
  float* z1   = (float*)(ws + 5880064);    // N*64
  float* W1P  = (float*)(ws + 8440064);    // 28*8192
  float* W2P  = (float*)(ws + 9357568);    // 28*8192 (end 10,275,072)

  hipMemsetAsync(ws, 0, 80000, stream);    // deg + cur
  k_count<<<625, 256, 0, stream>>>(ei, deg);
  k_pack<<<28, 256, 0, stream>>>(W1, W2, W1P, W2P);
  k_scan<<<1, 1024, 0, stream>>>(deg, offs);
  k_fill<<<625, 256, 0, stream>>>(ei, offs, cur, csr);
  k_encoder<<<1250, 256, 0, stream>>>(x, encW, encb, lng, lnb, h, z0);

  float* zc = z0;
  float* znx = z1;
  for (int l = 0; l < NLAYERS; l++) {
    int ln_next = (l + 1 < NLAYERS) ? (l + 1) : l;
    k_layer<<<1000, 256, 0, stream>>>(zc, znx, h, offs, csr, tv, W1P, W2P,
                                      b1, mg, mb, b2,
                                      lng + ln_next * H, lnb + ln_next * H,
                                      l, (l == NLAYERS - 1) ? 1 : 0);
    float* tmp = zc; zc = znx; znx = tmp;
  }
  k_head<<<1250, 256, 0, stream>>>(h, Wh, bh, (float*)d_out);
}

// Round 9
// 1587.652 us; speedup vs baseline: 1.0716x; 1.0716x over previous
//
#include <hip/hip_runtime.h>

#define N_NODES 10000
#define N_EDGES 160000
#define IN_CH 128
#define H 64
#define H2 128
#define OUT_CH 112
#define NLAYERS 28
#define LOG2E 1.44269504088896340736f

// async global->LDS, 16B per lane, LDS dest = wave-uniform base + lane*16
#define GLDS16(gp, lp) __builtin_amdgcn_global_load_lds( \
    (const __attribute__((address_space(1))) void*)(gp),  \
    (__attribute__((address_space(3))) void*)(lp), 16, 0, 0)

// ---------------- CSR build ----------------
__global__ __launch_bounds__(256) void k_count(const int* __restrict__ ei, int* __restrict__ deg) {
  int e = blockIdx.x * 256 + threadIdx.x;
  atomicAdd(&deg[ei[N_EDGES + e]], 1);   // E = 625*256 exactly
}

__global__ __launch_bounds__(1024) void k_scan(const int* __restrict__ deg, int* __restrict__ offs) {
  __shared__ int sums[1024];
  constexpr int CH = 10;
  int t = threadIdx.x;
  int base = t * CH;
  int local[CH];
  int s = 0;
  #pragma unroll
  for (int i = 0; i < CH; i++) {
    int idx = base + i;
    int v = (idx < N_NODES) ? deg[idx] : 0;
    local[i] = s; s += v;
  }
  sums[t] = s;
  __syncthreads();
  for (int off = 1; off < 1024; off <<= 1) {
    int v = (t >= off) ? sums[t - off] : 0;
    __syncthreads();
    sums[t] += v;
    __syncthreads();
  }
  int prev = (t == 0) ? 0 : sums[t - 1];
  #pragma unroll
  for (int i = 0; i < CH; i++) {
    int idx = base + i;
    if (idx < N_NODES) offs[idx] = prev + local[i];
  }
  if (t == 1023) offs[N_NODES] = sums[1023];
}

// csr stores BYTE offsets (src*H*4) to shave gather addressing
__global__ __launch_bounds__(256) void k_fill(const int* __restrict__ ei, const int* __restrict__ offs,
                                              int* __restrict__ cur, int* __restrict__ csr) {
  int e = blockIdx.x * 256 + threadIdx.x;
  int d = ei[N_EDGES + e];
  int p = offs[d] + atomicAdd(&cur[d], 1);
  csr[p] = ei[e] << 8;
}

// ---------------- weight packing ----------------
// W1P[l][g*512 + h*256 + lane*4 + e] = W1[l][(4g + h*2 + (e>>1))*128 + lane*2 + (e&1)]
//   -> LDS reads are contiguous 16B/lane slots (conflict-free ds_read_b128).
// W2P[l][(g*64+lane)*4 + j] = W2[l][(4g+j)*64 + lane]   (streamed from global)
__global__ __launch_bounds__(256) void k_pack(const float* __restrict__ W1, const float* __restrict__ W2,
                                              float* __restrict__ W1P, float* __restrict__ W2P) {
  int l = blockIdx.x;
  const float* w1 = W1 + l * 8192; float* p1 = W1P + l * 8192;
  const float* w2 = W2 + l * 8192; float* p2 = W2P + l * 8192;
  int t = threadIdx.x;
  for (int i = t; i < 8192; i += 256) {
    int g = i >> 9, r = i & 511;
    int hh = r >> 8, lane = (r >> 2) & 63, e = r & 3;
    p1[i] = w1[(4 * g + hh * 2 + (e >> 1)) * H2 + lane * 2 + (e & 1)];
  }
  for (int i = t; i < 8192; i += 256) {
    int g = i >> 8, r = i & 255;
    int lane = r >> 2, j = r & 3;
    p2[i] = w2[(4 * g + j) * H + lane];
  }
}

// ---------------- encoder: h = x@W+b ; z0 = relu(LN(h; g0,b0)) ----------------
__global__ __launch_bounds__(256) void k_encoder(
    const float* __restrict__ x, const float* __restrict__ Wenc, const float* __restrict__ benc,
    const float* __restrict__ lng, const float* __restrict__ lnb,
    float* __restrict__ h, float* __restrict__ z) {
  __shared__ float Xs[8][IN_CH];
  int t = threadIdx.x;
  int tile = blockIdx.x * 8;
  {
    int r = t >> 5, c4 = t & 31;
    float4 v = ((const float4*)x)[(tile + r) * 32 + c4];
    *(float4*)&Xs[r][c4 * 4] = v;
  }
  __syncthreads();
  int lane = t & 63;
  int wave = __builtin_amdgcn_readfirstlane(t >> 6);
  int n0 = wave * 2;
  float b = benc[lane];
  float a0 = b, a1 = b;
  #pragma unroll
  for (int k = 0; k < IN_CH; k += 4) {
    float4 X0 = *(float4*)&Xs[n0][k];
    float4 X1 = *(float4*)&Xs[n0 + 1][k];
    float w0 = Wenc[(k + 0) * H + lane];
    float w1 = Wenc[(k + 1) * H + lane];
    float w2 = Wenc[(k + 2) * H + lane];
    float w3 = Wenc[(k + 3) * H + lane];
    a0 = fmaf(X0.x, w0, a0); a0 = fmaf(X0.y, w1, a0); a0 = fmaf(X0.z, w2, a0); a0 = fmaf(X0.w, w3, a0);
    a1 = fmaf(X1.x, w0, a1); a1 = fmaf(X1.y, w1, a1); a1 = fmaf(X1.z, w2, a1); a1 = fmaf(X1.w, w3, a1);
  }
  float g = lng[lane], bb = lnb[lane];
  #pragma unroll
  for (int i = 0; i < 2; i++) {
    float a = (i == 0) ? a0 : a1;
    float s = a, q = a * a;
    #pragma unroll
    for (int m = 1; m < 64; m <<= 1) { s += __shfl_xor(s, m); q += __shfl_xor(q, m); }
    float mu = s * (1.0f / 64.0f);
    float var = q * (1.0f / 64.0f) - mu * mu;
    float rs = rsqrtf(var + 1e-5f);
    int gn = tile + n0 + i;
    h[gn * H + lane] = a;
    z[gn * H + lane] = fmaxf(fmaf((a - mu) * rs, g, bb), 0.f);
  }
}

// ---------------- fused GENConv layer ----------------
// 1000 blocks x 4 waves; waves 0,1 -> 3 nodes, waves 2,3 -> 2 nodes (10/block).
// W1 (32KB) async-staged to LDS under agg; W2 streamed from global (L1-hot).
// Gathers: sequential per node, 16-wide rounds (register-light; TLP hides latency).
__global__ __launch_bounds__(256, 3) void k_layer(
    const float* __restrict__ zc, float* __restrict__ zn, float* __restrict__ h,
    const int* __restrict__ offs, const int* __restrict__ csr,
    const float* __restrict__ tvec,
    const float* __restrict__ W1P, const float* __restrict__ W2P,
    const float* __restrict__ b1,
    const float* __restrict__ mg, const float* __restrict__ mb,
    const float* __restrict__ b2,
    const float* __restrict__ lngn, const float* __restrict__ lnbn,
    int l, int last) {
  __shared__ float Ws[8192];       // 32 KB W1
  __shared__ float Asl[10][H];     // 2.5 KB
  __shared__ float Us[10][H2];     // 5 KB
  int t = threadIdx.x;
  int lane = t & 63;
  int wave = __builtin_amdgcn_readfirstlane(t >> 6);
  int tile = blockIdx.x * 10;

  // async W1 stage (oldest in vmcnt queue; completes under agg)
  const float* W1Pl = W1P + (size_t)l * 8192;
  #pragma unroll
  for (int i = 0; i < 8; i++) {
    int off = (i * 256 + t) * 4;
    GLDS16(W1Pl + off, Ws + off);
  }

  int s = (wave < 2) ? wave * 3 : 6 + (wave - 2) * 2;
  int cnt = (wave < 2) ? 3 : 2;

  // ---- phase A: softmax aggregation ----
  float tl = tvec[l] * LOG2E;
  int e0[3], e1[3], nd[3];
  #pragma unroll
  for (int i = 0; i < 3; i++) {
    nd[i] = tile + s + ((i < cnt) ? i : cnt - 1);
    e0[i] = offs[nd[i]]; e1[i] = offs[nd[i] + 1];
  }
  float den[3] = {0.f, 0.f, 0.f}, acc[3] = {0.f, 0.f, 0.f};
  #pragma unroll
  for (int i = 0; i < 3; i++) {
    if (i < cnt) {
      for (int base = e0[i]; base < e1[i]; base += 16) {
        int idx[16]; float vv[16];
        #pragma unroll
        for (int j = 0; j < 16; j++) {
          int ee = base + j;
          idx[j] = csr[ee < e1[i] ? ee : e1[i] - 1];
        }
        #pragma unroll
        for (int j = 0; j < 16; j++)
          vv[j] = *(const float*)((const char*)zc + idx[j] + (lane << 2));
        #pragma unroll
        for (int j = 0; j < 16; j++) {
          float v = vv[j] + 1e-7f;
          float pz = (base + j < e1[i]) ? __builtin_amdgcn_exp2f(v * tl) : 0.f;
          den[i] += pz;
          acc[i] = fmaf(pz, v, acc[i]);
        }
      }
    }
  }
  #pragma unroll
  for (int i = 0; i < 3; i++) {
    if (i < cnt) {
      Asl[s + i][lane] = acc[i] / (den[i] + 1e-16f) + zc[nd[i] * H + lane];
    }
  }

  __syncthreads();   // drains vmcnt(0): W1 in LDS; Asl visible

  // ---- phase B: u1 = A @ W1 + b1 ; Us = relu(LN(u1)) ----
  {
    const float* b1l = b1 + l * H2;
    int c0 = lane * 2;
    float bb0 = b1l[c0], bb1 = b1l[c0 + 1];
    float u0[3], u1[3];
    #pragma unroll
    for (int i = 0; i < 3; i++) { u0[i] = bb0; u1[i] = bb1; }
    int r0 = s, r1 = s + 1, r2 = s + cnt - 1;
    #pragma unroll
    for (int g = 0; g < 16; g++) {
      float4 wa = *(float4*)&Ws[g * 512 + lane * 4];
      float4 wb = *(float4*)&Ws[g * 512 + 256 + lane * 4];
      float4 A0 = *(float4*)&Asl[r0][g * 4];
      float4 A1 = *(float4*)&Asl[r1][g * 4];
      float4 A2 = *(float4*)&Asl[r2][g * 4];
      u0[0] = fmaf(A0.x, wa.x, u0[0]); u1[0] = fmaf(A0.x, wa.y, u1[0]);
      u0[0] = fmaf(A0.y, wa.z, u0[0]); u1[0] = fmaf(A0.y, wa.w, u1[0]);
      u0[0] = fmaf(A0.z, wb.x, u0[0]); u1[0] = fmaf(A0.z, wb.y, u1[0]);
      u0[0] = fmaf(A0.w, wb.z, u0[0]); u1[0] = fmaf(A0.w, wb.w, u1[0]);
      u0[1] = fmaf(A1.x, wa.x, u0[1]); u1[1] = fmaf(A1.x, wa.y, u1[1]);
      u0[1] = fmaf(A1.y, wa.z, u0[1]); u1[1] = fmaf(A1.y, wa.w, u1[1]);
      u0[1] = fmaf(A1.z, wb.x, u0[1]); u1[1] = fmaf(A1.z, wb.y, u1[1]);
      u0[1] = fmaf(A1.w, wb.z, u0[1]); u1[1] = fmaf(A1.w, wb.w, u1[1]);
      u0[2] = fmaf(A2.x, wa.x, u0[2]); u1[2] = fmaf(A2.x, wa.y, u1[2]);
      u0[2] = fmaf(A2.y, wa.z, u0[2]); u1[2] = fmaf(A2.y, wa.w, u1[2]);
      u0[2] = fmaf(A2.z, wb.x, u0[2]); u1[2] = fmaf(A2.z, wb.y, u1[2]);
      u0[2] = fmaf(A2.w, wb.z, u0[2]); u1[2] = fmaf(A2.w, wb.w, u1[2]);
    }
    float sv[3], q[3];
    #pragma unroll
    for (int i = 0; i < 3; i++) { sv[i] = u0[i] + u1[i]; q[i] = u0[i] * u0[i] + u1[i] * u1[i]; }
    #pragma unroll
    for (int m = 1; m < 64; m <<= 1) {
      #pragma unroll
      for (int i = 0; i < 3; i++) { sv[i] += __shfl_xor(sv[i], m); q[i] += __shfl_xor(q[i], m); }
    }
    const float* mgl = mg + l * H2;
    const float* mbl = mb + l * H2;
    float g0 = mgl[c0], g1 = mgl[c0 + 1], hb0 = mbl[c0], hb1 = mbl[c0 + 1];
    #pragma unroll
    for (int i = 0; i < 3; i++) {
      if (i < cnt) {
        float mu = sv[i] * (1.0f / 128.0f);
        float rs = rsqrtf(q[i] * (1.0f / 128.0f) - mu * mu + 1e-5f);
        float o0 = fmaxf(fmaf((u0[i] - mu) * rs, g0, hb0), 0.f);
        float o1 = fmaxf(fmaf((u1[i] - mu) * rs, g1, hb1), 0.f);
        *(float2*)&Us[s + i][c0] = make_float2(o0, o1);
      }
    }
  }
  // no barrier: phase C reads only own-wave Us rows (same-wave LDS RAW -> lgkmcnt)

  // ---- phase C: u2 = Us @ W2 + b2 ; h += u2 ; phase D: z_next = relu(LN(h)) ----
  {
    const float* W2Pl = W2P + (size_t)l * 8192;
    const float* b2l = b2 + l * H;
    float bb = b2l[lane];
    float v[3];
    #pragma unroll
    for (int i = 0; i < 3; i++) v[i] = bb;
    int r0 = s, r1 = s + 1, r2 = s + cnt - 1;
    #pragma unroll
    for (int g = 0; g < 32; g++) {
      float4 w = *(const float4*)&W2Pl[(g * 64 + lane) * 4];
      float4 X0 = *(float4*)&Us[r0][g * 4];
      float4 X1 = *(float4*)&Us[r1][g * 4];
      float4 X2 = *(float4*)&Us[r2][g * 4];
      v[0] = fmaf(X0.x, w.x, v[0]); v[0] = fmaf(X0.y, w.y, v[0]);
      v[0] = fmaf(X0.z, w.z, v[0]); v[0] = fmaf(X0.w, w.w, v[0]);
      v[1] = fmaf(X1.x, w.x, v[1]); v[1] = fmaf(X1.y, w.y, v[1]);
      v[1] = fmaf(X1.z, w.z, v[1]); v[1] = fmaf(X1.w, w.w, v[1]);
      v[2] = fmaf(X2.x, w.x, v[2]); v[2] = fmaf(X2.y, w.y, v[2]);
      v[2] = fmaf(X2.z, w.z, v[2]); v[2] = fmaf(X2.w, w.w, v[2]);
    }
    float gg = lngn[lane], gb = lnbn[lane];
    #pragma unroll
    for (int i = 0; i < 3; i++) {
      if (i < cnt) {
        int gn = nd[i];
        float hv = h[gn * H + lane] + v[i];
        h[gn * H + lane] = hv;
        if (!last) {
          float sv = hv, q = hv * hv;
          #pragma unroll
          for (int m = 1; m < 64; m <<= 1) { sv += __shfl_xor(sv, m); q += __shfl_xor(q, m); }
          float mu = sv * (1.0f / 64.0f);
          float rs = rsqrtf(q * (1.0f / 64.0f) - mu * mu + 1e-5f);
          zn[gn * H + lane] = fmaxf(fmaf((hv - mu) * rs, gg, gb), 0.f);
        }
      }
    }
  }
}

// ---------------- head: out = h @ Wh + bh ----------------
__global__ __launch_bounds__(256) void k_head(const float* __restrict__ h, const float* __restrict__ Wh,
                                              const float* __restrict__ bh, float* __restrict__ out) {
  __shared__ float Hs[8][H];
  int t = threadIdx.x;
  int tile = blockIdx.x * 8;
  if (t < 128) {
    int r = t >> 4, c4 = t & 15;
    float4 v = ((const float4*)h)[(tile + r) * 16 + c4];
    *(float4*)&Hs[r][c4 * 4] = v;
  }
  __syncthreads();
  int lane = t & 63;
  int wave = __builtin_amdgcn_readfirstlane(t >> 6);
  int n0 = wave * 2;
  int c2 = 64 + ((lane < 48) ? lane : 47);
  float b0 = bh[lane], b1 = bh[c2];
  float a00 = b0, a01 = b1, a10 = b0, a11 = b1;
  #pragma unroll
  for (int k = 0; k < H; k += 4) {
    float4 X0 = *(float4*)&Hs[n0][k];
    float4 X1 = *(float4*)&Hs[n0 + 1][k];
    float wA0 = Wh[(k + 0) * OUT_CH + lane], wB0 = Wh[(k + 0) * OUT_CH + c2];
    float wA1 = Wh[(k + 1) * OUT_CH + lane], wB1 = Wh[(k + 1) * OUT_CH + c2];
    float wA2 = Wh[(k + 2) * OUT_CH + lane], wB2 = Wh[(k + 2) * OUT_CH + c2];
    float wA3 = Wh[(k + 3) * OUT_CH + lane], wB3 = Wh[(k + 3) * OUT_CH + c2];
    a00 = fmaf(X0.x, wA0, a00); a01 = fmaf(X0.x, wB0, a01);
    a00 = fmaf(X0.y, wA1, a00); a01 = fmaf(X0.y, wB1, a01);
    a00 = fmaf(X0.z, wA2, a00); a01 = fmaf(X0.z, wB2, a01);
    a00 = fmaf(X0.w, wA3, a00); a01 = fmaf(X0.w, wB3, a01);
    a10 = fmaf(X1.x, wA0, a10); a11 = fmaf(X1.x, wB0, a11);
    a10 = fmaf(X1.y, wA1, a10); a11 = fmaf(X1.y, wB1, a11);
    a10 = fmaf(X1.z, wA2, a10); a11 = fmaf(X1.z, wB2, a11);
    a10 = fmaf(X1.w, wA3, a10); a11 = fmaf(X1.w, wB3, a11);
  }
  int gn0 = tile + n0;
  out[gn0 * OUT_CH + lane] = a00;
  out[(gn0 + 1) * OUT_CH + lane] = a10;
  if (lane < 48) {
    out[gn0 * OUT_CH + 64 + lane] = a01;
    out[(gn0 + 1) * OUT_CH + 64 + lane] = a11;
  }
}

extern "C" void kernel_launch(void* const* d_in, const int* in_sizes, int n_in,
                              void* d_out, int out_size, void* d_ws, size_t ws_size,
                              hipStream_t stream) {
  (void)in_sizes; (void)n_in; (void)out_size; (void)ws_size;
  const float* x    = (const float*)d_in[0];
  const int*   ei   = (const int*)d_in[1];
  const float* encW = (const float*)d_in[2];
  const float* encb = (const float*)d_in[3];
  const float* lng  = (const float*)d_in[4];
  const float* lnb  = (const float*)d_in[5];
  const float* tv   = (const float*)d_in[6];
  const float* W1   = (const float*)d_in[7];
  const float* b1   = (const float*)d_in[8];
  const float* mg   = (const float*)d_in[9];
  const float* mb   = (const float*)d_in[10];
  const float* W2   = (const float*)d_in[11];
  const float* b2   = (const float*)d_in[12];
  const float* Wh   = (const float*)d_in[13];
  const float* bh   = (const float*)d_in[14];

  char* ws = (char*)d_ws;
  int*   deg  = (int*)(ws + 0);            // N ints
  int*   cur  = (int*)(ws + 40000);        // N ints
  int*   offs = (int*)(ws + 80000);        // N+1 ints
  int*   csr  = (int*)(ws + 120064);       // E ints (byte offsets)
  float* h    = (float*)(ws + 760064);     // N*64
  float* z0   = (float*)(ws + 3320064);    // N*64
  float* z1   = (float*)(ws + 5880064);    // N*64
  float* W1P  = (float*)(ws + 8440064);    // 28*8192
  float* W2P  = (float*)(ws + 9357568);    // 28*8192 (end 10,275,072)

  hipMemsetAsync(ws, 0, 80000, stream);    // deg + cur
  k_count<<<625, 256, 0, stream>>>(ei, deg);
  k_pack<<<28, 256, 0, stream>>>(W1, W2, W1P, W2P);
  k_scan<<<1, 1024, 0, stream>>>(deg, offs);
  k_fill<<<625, 256, 0, stream>>>(ei, offs, cur, csr);
  k_encoder<<<1250, 256, 0, stream>>>(x, encW, encb, lng, lnb, h, z0);

  float* zc = z0;
  float* znx = z1;
  for (int l = 0; l < NLAYERS; l++) {
    int ln_next = (l + 1 < NLAYERS) ? (l + 1) : l;
    k_layer<<<1000, 256, 0, stream>>>(zc, znx, h, offs, csr, tv, W1P, W2P,
                                      b1, mg, mb, b2,
                                      lng + ln_next * H, lnb + ln_next * H,
                                      l, (l == NLAYERS - 1) ? 1 : 0);
    float* tmp = zc; zc = znx; znx = tmp;
  }
  k_head<<<1250, 256, 0, stream>>>(h, Wh, bh, (float*)d_out);
}

// Round 10
// 1346.838 us; speedup vs baseline: 1.2632x; 1.1788x over previous
//
#include <hip/hip_runtime.h>

#define N_NODES 10000
#define N_EDGES 160000
#define IN_CH 128
#define H 64
#define H2 128
#define OUT_CH 112
#define NLAYERS 28
#define LOG2E 1.44269504088896340736f

// async global->LDS, 16B per lane, LDS dest = wave-uniform base + lane*16
#define GLDS16(gp, lp) __builtin_amdgcn_global_load_lds( \
    (const __attribute__((address_space(1))) void*)(gp),  \
    (__attribute__((address_space(3))) void*)(lp), 16, 0, 0)

// ---------------- CSR build ----------------
__global__ __launch_bounds__(256) void k_count(const int* __restrict__ ei, int* __restrict__ deg) {
  int e = blockIdx.x * 256 + threadIdx.x;
  atomicAdd(&deg[ei[N_EDGES + e]], 1);   // E = 625*256 exactly
}

__global__ __launch_bounds__(1024) void k_scan(const int* __restrict__ deg, int* __restrict__ offs) {
  __shared__ int sums[1024];
  constexpr int CH = 10;
  int t = threadIdx.x;
  int base = t * CH;
  int local[CH];
  int s = 0;
  #pragma unroll
  for (int i = 0; i < CH; i++) {
    int idx = base + i;
    int v = (idx < N_NODES) ? deg[idx] : 0;
    local[i] = s; s += v;
  }
  sums[t] = s;
  __syncthreads();
  for (int off = 1; off < 1024; off <<= 1) {
    int v = (t >= off) ? sums[t - off] : 0;
    __syncthreads();
    sums[t] += v;
    __syncthreads();
  }
  int prev = (t == 0) ? 0 : sums[t - 1];
  #pragma unroll
  for (int i = 0; i < CH; i++) {
    int idx = base + i;
    if (idx < N_NODES) offs[idx] = prev + local[i];
  }
  if (t == 1023) offs[N_NODES] = sums[1023];
}

// csr stores BYTE offsets (src*H*4) to shave gather addressing
__global__ __launch_bounds__(256) void k_fill(const int* __restrict__ ei, const int* __restrict__ offs,
                                              int* __restrict__ cur, int* __restrict__ csr) {
  int e = blockIdx.x * 256 + threadIdx.x;
  int d = ei[N_EDGES + e];
  int p = offs[d] + atomicAdd(&cur[d], 1);
  csr[p] = ei[e] << 8;
}

// ---------------- weight packing ----------------
// W1P[l][g*512 + h*256 + lane*4 + e] = W1[l][(4g + h*2 + (e>>1))*128 + lane*2 + (e&1)]
//   -> LDS reads are contiguous 16B/lane slots (conflict-free ds_read_b128).
// W2P[l][(g*64+lane)*4 + j] = W2[l][(4g+j)*64 + lane]   (streamed from global)
__global__ __launch_bounds__(256) void k_pack(const float* __restrict__ W1, const float* __restrict__ W2,
                                              float* __restrict__ W1P, float* __restrict__ W2P) {
  int l = blockIdx.x;
  const float* w1 = W1 + l * 8192; float* p1 = W1P + l * 8192;
  const float* w2 = W2 + l * 8192; float* p2 = W2P + l * 8192;
  int t = threadIdx.x;
  for (int i = t; i < 8192; i += 256) {
    int g = i >> 9, r = i & 511;
    int hh = r >> 8, lane = (r >> 2) & 63, e = r & 3;
    p1[i] = w1[(4 * g + hh * 2 + (e >> 1)) * H2 + lane * 2 + (e & 1)];
  }
  for (int i = t; i < 8192; i += 256) {
    int g = i >> 8, r = i & 255;
    int lane = r >> 2, j = r & 3;
    p2[i] = w2[(4 * g + j) * H + lane];
  }
}

// ---------------- encoder: h = x@W+b ; z0 = relu(LN(h; g0,b0)) ----------------
__global__ __launch_bounds__(256) void k_encoder(
    const float* __restrict__ x, const float* __restrict__ Wenc, const float* __restrict__ benc,
    const float* __restrict__ lng, const float* __restrict__ lnb,
    float* __restrict__ h, float* __restrict__ z) {
  __shared__ float Xs[8][IN_CH];
  int t = threadIdx.x;
  int tile = blockIdx.x * 8;
  {
    int r = t >> 5, c4 = t & 31;
    float4 v = ((const float4*)x)[(tile + r) * 32 + c4];
    *(float4*)&Xs[r][c4 * 4] = v;
  }
  __syncthreads();
  int lane = t & 63;
  int wave = __builtin_amdgcn_readfirstlane(t >> 6);
  int n0 = wave * 2;
  float b = benc[lane];
  float a0 = b, a1 = b;
  #pragma unroll
  for (int k = 0; k < IN_CH; k += 4) {
    float4 X0 = *(float4*)&Xs[n0][k];
    float4 X1 = *(float4*)&Xs[n0 + 1][k];
    float w0 = Wenc[(k + 0) * H + lane];
    float w1 = Wenc[(k + 1) * H + lane];
    float w2 = Wenc[(k + 2) * H + lane];
    float w3 = Wenc[(k + 3) * H + lane];
    a0 = fmaf(X0.x, w0, a0); a0 = fmaf(X0.y, w1, a0); a0 = fmaf(X0.z, w2, a0); a0 = fmaf(X0.w, w3, a0);
    a1 = fmaf(X1.x, w0, a1); a1 = fmaf(X1.y, w1, a1); a1 = fmaf(X1.z, w2, a1); a1 = fmaf(X1.w, w3, a1);
  }
  float g = lng[lane], bb = lnb[lane];
  #pragma unroll
  for (int i = 0; i < 2; i++) {
    float a = (i == 0) ? a0 : a1;
    float s = a, q = a * a;
    #pragma unroll
    for (int m = 1; m < 64; m <<= 1) { s += __shfl_xor(s, m); q += __shfl_xor(q, m); }
    float mu = s * (1.0f / 64.0f);
    float var = q * (1.0f / 64.0f) - mu * mu;
    float rs = rsqrtf(var + 1e-5f);
    int gn = tile + n0 + i;
    h[gn * H + lane] = a;
    z[gn * H + lane] = fmaxf(fmaf((a - mu) * rs, g, bb), 0.f);
  }
}

// ---------------- fused GENConv layer ----------------
// 1000 blocks x 4 waves; waves 0,1 -> 3 nodes, waves 2,3 -> 2 nodes (10/block).
// W1 (32KB) async-staged to LDS under agg; W2 streamed from global (L1-hot).
// NO min-waves launch bound: R8/R9 showed it caps VGPRs at 256/waves -> scratch spill.
__global__ __launch_bounds__(256) void k_layer(
    const float* __restrict__ zc, float* __restrict__ zn, float* __restrict__ h,
    const int* __restrict__ offs, const int* __restrict__ csr,
    const float* __restrict__ tvec,
    const float* __restrict__ W1P, const float* __restrict__ W2P,
    const float* __restrict__ b1,
    const float* __restrict__ mg, const float* __restrict__ mb,
    const float* __restrict__ b2,
    const float* __restrict__ lngn, const float* __restrict__ lnbn,
    int l, int last) {
  __shared__ float Ws[8192];       // 32 KB W1
  __shared__ float Asl[10][H];     // 2.5 KB
  __shared__ float Us[10][H2];     // 5 KB  (total 40448 B -> 4 blocks/CU by LDS)
  int t = threadIdx.x;
  int lane = t & 63;
  int wave = __builtin_amdgcn_readfirstlane(t >> 6);
  int tile = blockIdx.x * 10;

  // async W1 stage (oldest in vmcnt queue; completes under agg)
  const float* W1Pl = W1P + (size_t)l * 8192;
  #pragma unroll
  for (int i = 0; i < 8; i++) {
    int off = (i * 256 + t) * 4;
    GLDS16(W1Pl + off, Ws + off);
  }

  int s = (wave < 2) ? wave * 3 : 6 + (wave - 2) * 2;
  int cnt = (wave < 2) ? 3 : 2;

  // ---- phase A: softmax aggregation (sequential per node, 16-wide rounds) ----
  float tl = tvec[l] * LOG2E;
  int e0[3], e1[3], nd[3];
  #pragma unroll
  for (int i = 0; i < 3; i++) {
    nd[i] = tile + s + ((i < cnt) ? i : cnt - 1);
    e0[i] = offs[nd[i]]; e1[i] = offs[nd[i] + 1];
  }
  float den[3] = {0.f, 0.f, 0.f}, acc[3] = {0.f, 0.f, 0.f};
  #pragma unroll
  for (int i = 0; i < 3; i++) {
    if (i < cnt) {
      for (int base = e0[i]; base < e1[i]; base += 16) {
        int idx[16]; float vv[16];
        #pragma unroll
        for (int j = 0; j < 16; j++) {
          int ee = base + j;
          idx[j] = csr[ee < e1[i] ? ee : e1[i] - 1];
        }
        #pragma unroll
        for (int j = 0; j < 16; j++)
          vv[j] = *(const float*)((const char*)zc + idx[j] + (lane << 2));
        #pragma unroll
        for (int j = 0; j < 16; j++) {
          float v = vv[j] + 1e-7f;
          float pz = (base + j < e1[i]) ? __builtin_amdgcn_exp2f(v * tl) : 0.f;
          den[i] += pz;
          acc[i] = fmaf(pz, v, acc[i]);
        }
      }
    }
  }
  #pragma unroll
  for (int i = 0; i < 3; i++) {
    if (i < cnt) {
      Asl[s + i][lane] = acc[i] / (den[i] + 1e-16f) + zc[nd[i] * H + lane];
    }
  }

  __syncthreads();   // drains vmcnt(0): W1 in LDS; Asl visible

  // ---- phase B: u1 = A @ W1 + b1 ; Us = relu(LN(u1)) ----
  {
    const float* b1l = b1 + l * H2;
    int c0 = lane * 2;
    float bb0 = b1l[c0], bb1 = b1l[c0 + 1];
    float u0[3], u1[3];
    #pragma unroll
    for (int i = 0; i < 3; i++) { u0[i] = bb0; u1[i] = bb1; }
    int r0 = s, r1 = s + 1, r2 = s + cnt - 1;
    #pragma unroll
    for (int g = 0; g < 16; g++) {
      float4 wa = *(float4*)&Ws[g * 512 + lane * 4];
      float4 wb = *(float4*)&Ws[g * 512 + 256 + lane * 4];
      float4 A0 = *(float4*)&Asl[r0][g * 4];
      float4 A1 = *(float4*)&Asl[r1][g * 4];
      float4 A2 = *(float4*)&Asl[r2][g * 4];
      u0[0] = fmaf(A0.x, wa.x, u0[0]); u1[0] = fmaf(A0.x, wa.y, u1[0]);
      u0[0] = fmaf(A0.y, wa.z, u0[0]); u1[0] = fmaf(A0.y, wa.w, u1[0]);
      u0[0] = fmaf(A0.z, wb.x, u0[0]); u1[0] = fmaf(A0.z, wb.y, u1[0]);
      u0[0] = fmaf(A0.w, wb.z, u0[0]); u1[0] = fmaf(A0.w, wb.w, u1[0]);
      u0[1] = fmaf(A1.x, wa.x, u0[1]); u1[1] = fmaf(A1.x, wa.y, u1[1]);
      u0[1] = fmaf(A1.y, wa.z, u0[1]); u1[1] = fmaf(A1.y, wa.w, u1[1]);
      u0[1] = fmaf(A1.z, wb.x, u0[1]); u1[1] = fmaf(A1.z, wb.y, u1[1]);
      u0[1] = fmaf(A1.w, wb.z, u0[1]); u1[1] = fmaf(A1.w, wb.w, u1[1]);
      u0[2] = fmaf(A2.x, wa.x, u0[2]); u1[2] = fmaf(A2.x, wa.y, u1[2]);
      u0[2] = fmaf(A2.y, wa.z, u0[2]); u1[2] = fmaf(A2.y, wa.w, u1[2]);
      u0[2] = fmaf(A2.z, wb.x, u0[2]); u1[2] = fmaf(A2.z, wb.y, u1[2]);
      u0[2] = fmaf(A2.w, wb.z, u0[2]); u1[2] = fmaf(A2.w, wb.w, u1[2]);
    }
    float sv[3], q[3];
    #pragma unroll
    for (int i = 0; i < 3; i++) { sv[i] = u0[i] + u1[i]; q[i] = u0[i] * u0[i] + u1[i] * u1[i]; }
    #pragma unroll
    for (int m = 1; m < 64; m <<= 1) {
      #pragma unroll
      for (int i = 0; i < 3; i++) { sv[i] += __shfl_xor(sv[i], m); q[i] += __shfl_xor(q[i], m); }
    }
    const float* mgl = mg + l * H2;
    const float* mbl = mb + l * H2;
    float g0 = mgl[c0], g1 = mgl[c0 + 1], hb0 = mbl[c0], hb1 = mbl[c0 + 1];
    #pragma unroll
    for (int i = 0; i < 3; i++) {
      if (i < cnt) {
        float mu = sv[i] * (1.0f / 128.0f);
        float rs = rsqrtf(q[i] * (1.0f / 128.0f) - mu * mu + 1e-5f);
        float o0 = fmaxf(fmaf((u0[i] - mu) * rs, g0, hb0), 0.f);
        float o1 = fmaxf(fmaf((u1[i] - mu) * rs, g1, hb1), 0.f);
        *(float2*)&Us[s + i][c0] = make_float2(o0, o1);
      }
    }
  }
  // no barrier: phase C reads only own-wave Us rows (same-wave LDS RAW -> lgkmcnt)

  // ---- phase C: u2 = Us @ W2 + b2 ; h += u2 ; phase D: z_next = relu(LN(h)) ----
  {
    const float* W2Pl = W2P + (size_t)l * 8192;
    const float* b2l = b2 + l * H;
    float bb = b2l[lane];
    float v[3];
    #pragma unroll
    for (int i = 0; i < 3; i++) v[i] = bb;
    int r0 = s, r1 = s + 1, r2 = s + cnt - 1;
    #pragma unroll
    for (int g = 0; g < 32; g++) {
      float4 w = *(const float4*)&W2Pl[(g * 64 + lane) * 4];
      float4 X0 = *(float4*)&Us[r0][g * 4];
      float4 X1 = *(float4*)&Us[r1][g * 4];
      float4 X2 = *(float4*)&Us[r2][g * 4];
      v[0] = fmaf(X0.x, w.x, v[0]); v[0] = fmaf(X0.y, w.y, v[0]);
      v[0] = fmaf(X0.z, w.z, v[0]); v[0] = fmaf(X0.w, w.w, v[0]);
      v[1] = fmaf(X1.x, w.x, v[1]); v[1] = fmaf(X1.y, w.y, v[1]);
      v[1] = fmaf(X1.z, w.z, v[1]); v[1] = fmaf(X1.w, w.w, v[1]);
      v[2] = fmaf(X2.x, w.x, v[2]); v[2] = fmaf(X2.y, w.y, v[2]);
      v[2] = fmaf(X2.z, w.z, v[2]); v[2] = fmaf(X2.w, w.w, v[2]);
    }
    float gg = lngn[lane], gb = lnbn[lane];
    #pragma unroll
    for (int i = 0; i < 3; i++) {
      if (i < cnt) {
        int gn = nd[i];
        float hv = h[gn * H + lane] + v[i];
        h[gn * H + lane] = hv;
        if (!last) {
          float sv = hv, q = hv * hv;
          #pragma unroll
          for (int m = 1; m < 64; m <<= 1) { sv += __shfl_xor(sv, m); q += __shfl_xor(q, m); }
          float mu = sv * (1.0f / 64.0f);
          float rs = rsqrtf(q * (1.0f / 64.0f) - mu * mu + 1e-5f);
          zn[gn * H + lane] = fmaxf(fmaf((hv - mu) * rs, gg, gb), 0.f);
        }
      }
    }
  }
}

// ---------------- head: out = h @ Wh + bh ----------------
__global__ __launch_bounds__(256) void k_head(const float* __restrict__ h, const float* __restrict__ Wh,
                                              const float* __restrict__ bh, float* __restrict__ out) {
  __shared__ float Hs[8][H];
  int t = threadIdx.x;
  int tile = blockIdx.x * 8;
  if (t < 128) {
    int r = t >> 4, c4 = t & 15;
    float4 v = ((const float4*)h)[(tile + r) * 16 + c4];
    *(float4*)&Hs[r][c4 * 4] = v;
  }
  __syncthreads();
  int lane = t & 63;
  int wave = __builtin_amdgcn_readfirstlane(t >> 6);
  int n0 = wave * 2;
  int c2 = 64 + ((lane < 48) ? lane : 47);
  float b0 = bh[lane], b1 = bh[c2];
  float a00 = b0, a01 = b1, a10 = b0, a11 = b1;
  #pragma unroll
  for (int k = 0; k < H; k += 4) {
    float4 X0 = *(float4*)&Hs[n0][k];
    float4 X1 = *(float4*)&Hs[n0 + 1][k];
    float wA0 = Wh[(k + 0) * OUT_CH + lane], wB0 = Wh[(k + 0) * OUT_CH + c2];
    float wA1 = Wh[(k + 1) * OUT_CH + lane], wB1 = Wh[(k + 1) * OUT_CH + c2];
    float wA2 = Wh[(k + 2) * OUT_CH + lane], wB2 = Wh[(k + 2) * OUT_CH + c2];
    float wA3 = Wh[(k + 3) * OUT_CH + lane], wB3 = Wh[(k + 3) * OUT_CH + c2];
    a00 = fmaf(X0.x, wA0, a00); a01 = fmaf(X0.x, wB0, a01);
    a00 = fmaf(X0.y, wA1, a00); a01 = fmaf(X0.y, wB1, a01);
    a00 = fmaf(X0.z, wA2, a00); a01 = fmaf(X0.z, wB2, a01);
    a00 = fmaf(X0.w, wA3, a00); a01 = fmaf(X0.w, wB3, a01);
    a10 = fmaf(X1.x, wA0, a10); a11 = fmaf(X1.x, wB0, a11);
    a10 = fmaf(X1.y, wA1, a10); a11 = fmaf(X1.y, wB1, a11);
    a10 = fmaf(X1.z, wA2, a10); a11 = fmaf(X1.z, wB2, a11);
    a10 = fmaf(X1.w, wA3, a10); a11 = fmaf(X1.w, wB3, a11);
  }
  int gn0 = tile + n0;
  out[gn0 * OUT_CH + lane] = a00;
  out[(gn0 + 1) * OUT_CH + lane] = a10;
  if (lane < 48) {
    out[gn0 * OUT_CH + 64 + lane] = a01;
    out[(gn0 + 1) * OUT_CH + 64 + lane] = a11;
  }
}

extern "C" void kernel_launch(void* const* d_in, const int* in_sizes, int n_in,
                              void* d_out, int out_size, void* d_ws, size_t ws_size,
                              hipStream_t stream) {
  (void)in_sizes; (void)n_in; (void)out_size; (void)ws_size;
  const float* x    = (const float*)d_in[0];
  const int*   ei   = (const int*)d_in[1];
  const float* encW = (const float*)d_in[2];
  const float* encb = (const float*)d_in[3];
  const float* lng  = (const float*)d_in[4];
  const float* lnb  = (const float*)d_in[5];
  const float* tv   = (const float*)d_in[6];
  const float* W1   = (const float*)d_in[7];
  const float* b1   = (const float*)d_in[8];
  const float* mg   = (const float*)d_in[9];
  const float* mb   = (const float*)d_in[10];
  const float* W2   = (const float*)d_in[11];
  const float* b2   = (const float*)d_in[12];
  const float* Wh   = (const float*)d_in[13];
  const float* bh   = (const float*)d_in[14];

  char* ws = (char*)d_ws;
  int*   deg  = (int*)(ws + 0);            // N ints
  int*   cur  = (int*)(ws + 40000);        // N ints
  int*   offs = (int*)(ws + 80000);        // N+1 ints
  int*   csr  = (int*)(ws + 120064);       // E ints (byte offsets)
  float* h    = (float*)(ws + 760064);     // N*64
  float* z0   = (float*)(ws + 3320064);    // N*64
  float* z1   = (float*)(ws + 5880064);    // N*64
  float* W1P  = (float*)(ws + 8440064);    // 28*8192
  float* W2P  = (float*)(ws + 9357568);    // 28*8192 (end 10,275,072)

  hipMemsetAsync(ws, 0, 80000, stream);    // deg + cur
  k_count<<<625, 256, 0, stream>>>(ei, deg);
  k_pack<<<28, 256, 0, stream>>>(W1, W2, W1P, W2P);
  k_scan<<<1, 1024, 0, stream>>>(deg, offs);
  k_fill<<<625, 256, 0, stream>>>(ei, offs, cur, csr);
  k_encoder<<<1250, 256, 0, stream>>>(x, encW, encb, lng, lnb, h, z0);

  float* zc = z0;
  float* znx = z1;
  for (int l = 0; l < NLAYERS; l++) {
    int ln_next = (l + 1 < NLAYERS) ? (l + 1) : l;
    k_layer<<<1000, 256, 0, stream>>>(zc, znx, h, offs, csr, tv, W1P, W2P,
                                      b1, mg, mb, b2,
                                      lng + ln_next * H, lnb + ln_next * H,
                                      l, (l == NLAYERS - 1) ? 1 : 0);
    float* tmp = zc; zc = znx; znx = tmp;
  }
  k_head<<<1250, 256, 0, stream>>>(h, Wh, bh, (float*)d_out);
}